// Round 4
// baseline (231.880 us; speedup 1.0000x reference)
//
#include <hip/hip_runtime.h>

typedef unsigned short u16;
typedef short bf16x8 __attribute__((ext_vector_type(8)));
typedef float f32x4 __attribute__((ext_vector_type(4)));

#define CM 256

__device__ inline u16 f2bf(float f) {
    union { float f; unsigned u; } v; v.f = f;
    unsigned r = v.u + 0x7fffu + ((v.u >> 16) & 1u);
    return (u16)(r >> 16);
}

// ---------------------------------------------------------------------------
// k'' bit-interleave for the stage2->stage3 contraction index (c,e):
//   k''[0,1]=c[0,1]  k''[2]=e[0]  k''[3]=c[2]  k''[4:6]=e[1:3]
//   k''[7]=c[3]      k''[8]=e[4]  k''[9]=c[4]
// Any k-order is valid as long as outer_s writes and Wo_t agree. This order
// makes kB's epilogue stores (regs = 4 consecutive c) an 8B ushort4 AND
// spreads both stores and a3 b128 reads uniformly over LDS banks when
// combined with the XOR swizzle  pi = (k''>>3) ^ (p&7).
// ---------------------------------------------------------------------------

// kW: one-time prep.
//  bid<512 : Wo[1024 ce][128 z] fp32 -> Wo_t[z][k''] bf16 (permuted)
//  bid<576 : Wa/Wb -> Wab_t[n][256 k] bf16 (n<32: Wa col, else Wb col)
//  else    : norm[i][j] = eps + sum_s mask[s,i]*mask[s,j]
__global__ void kW(const float* __restrict__ Wo, const float* __restrict__ Wa,
                   const float* __restrict__ Wb, const float* __restrict__ mask,
                   u16* __restrict__ Wo_t, u16* __restrict__ Wab_t,
                   float* __restrict__ norm_ws)
{
    int bid = blockIdx.x, t = threadIdx.x;
    if (bid < 512) {
        int idx = bid * 256 + t;            // idx = ce*128 + z (coalesced read)
        int ce = idx >> 7, z = idx & 127;
        int c = ce >> 5, e = ce & 31;
        int kpp = (c & 3) | ((e & 1) << 2) | (((c >> 2) & 1) << 3)
                | (((e >> 1) & 7) << 4) | (((c >> 3) & 1) << 7)
                | ((e >> 4) << 8) | ((c >> 4) << 9);
        Wo_t[z * 1024 + kpp] = f2bf(Wo[idx]);
    } else if (bid < 576) {
        int idx = (bid - 512) * 256 + t;    // idx = n*256 + k
        int n = idx >> 8, k = idx & 255;
        float v = (n < 32) ? Wa[k * 32 + n] : Wb[k * 32 + (n - 32)];
        Wab_t[idx] = f2bf(v);
    } else {
        int i = bid - 576, j = t;           // 256 blocks
        float acc = 1e-3f;
        for (int s = 0; s < 128; s++)
            acc += mask[s * 256 + i] * mask[s * 256 + j];
        norm_ws[i * 256 + j] = acc;
    }
}

// ---------------------------------------------------------------------------
// kA: LayerNorm + dual projection. 64 rows (one s, 64 i) per block, grid 512.
// Outputs transposed: a_t[(i*32+c)*128 + s] bf16. LDS 33,792 B.
// ---------------------------------------------------------------------------
__global__ __launch_bounds__(256, 2) void kA(
    const float* __restrict__ m, const float* __restrict__ mask,
    const float* __restrict__ ln_g, const float* __restrict__ ln_b,
    const u16* __restrict__ Wab_t, const float* __restrict__ ba,
    const float* __restrict__ bb,
    u16* __restrict__ a_t, u16* __restrict__ b_t)
{
    __shared__ u16 mn_s[64 * 264];   // [row][k], stride 264 (pad 8)

    const int t = threadIdx.x;
    const int w = t >> 6, lane = t & 63, quad = lane >> 4, lr = lane & 15;
    const int r0 = blockIdx.x * 64;

    bf16x8 wf[8];
    for (int ks = 0; ks < 8; ks++)
        wf[ks] = *(const bf16x8*)(Wab_t + (w * 16 + lr) * 256 + ks * 32 + quad * 8);

    const float4 g4  = ((const float4*)ln_g)[lane];
    const float4 be4 = ((const float4*)ln_b)[lane];

    for (int rr = 0; rr < 16; rr++) {
        int r = w * 16 + rr;
        float4 x = ((const float4*)m)[(r0 + r) * 64 + lane];
        float s1 = x.x + x.y + x.z + x.w;
        float s2 = x.x * x.x + x.y * x.y + x.z * x.z + x.w * x.w;
        for (int off = 32; off; off >>= 1) {
            s1 += __shfl_xor(s1, off);
            s2 += __shfl_xor(s2, off);
        }
        float mu = s1 * (1.f / CM);
        float rstd = rsqrtf(s2 * (1.f / CM) - mu * mu + 1e-5f);
        ushort4 o;
        o.x = f2bf((x.x - mu) * rstd * g4.x + be4.x);
        o.y = f2bf((x.y - mu) * rstd * g4.y + be4.y);
        o.z = f2bf((x.z - mu) * rstd * g4.z + be4.z);
        o.w = f2bf((x.w - mu) * rstd * g4.w + be4.w);
        *(ushort4*)(&mn_s[r * 264 + lane * 4]) = o;
    }
    __syncthreads();

    f32x4 acc[4] = {};
    for (int ks = 0; ks < 8; ks++)
        for (int mt = 0; mt < 4; mt++) {
            bf16x8 af = *(const bf16x8*)(&mn_s[(mt * 16 + lr) * 264 + ks * 32 + quad * 8]);
            acc[mt] = __builtin_amdgcn_mfma_f32_16x16x32_bf16(af, wf[ks], acc[mt], 0, 0, 0);
        }

    const int n = w * 16 + lr;
    const int cc = n & 31;
    const bool isB = n >= 32;
    const float bv = isB ? bb[cc] : ba[cc];
    u16* dst = isB ? b_t : a_t;
    for (int mt = 0; mt < 4; mt++)
        for (int reg = 0; reg < 4; reg++) {
            int r = mt * 16 + quad * 4 + reg;
            int row = r0 + r;
            int s = row >> 8, i = row & 255;
            float val = (acc[mt][reg] + bv) * mask[row];
            dst[(i * 32 + cc) * 128 + s] = f2bf(val);
        }
}

// ---------------------------------------------------------------------------
// kB: fused outer-product + Wo projection. Tile 4i x 8j (32 pairs), grid
// (64,32), 256 thr. NO LDS staging for a/b (each value is used once per wave
// from registers — fragments load straight from global b128, L2-hot). One
// barrier total. Outer tile lives in LDS as bf16 [32 p][1024 k''] with
// bit-interleaved k'' + XOR chunk swizzle -> conflict-free stores AND reads.
// Stage 3: M=32, K=1024, N=128 (32/wave), depth-2 Wo_t prefetch.
// LDS: 65,536 B. Regs: acc2 128 AGPR + ~100 VGPR -> 2 blocks/CU.
// ---------------------------------------------------------------------------
__global__ __launch_bounds__(256, 2) void kB(
    const u16* __restrict__ a_t, const u16* __restrict__ b_t,
    const u16* __restrict__ Wo_t, const float* __restrict__ bo,
    const float* __restrict__ norm_ws, float* __restrict__ out)
{
    __shared__ __align__(16) u16 outer_s[32 * 1024];   // 64 KB

    const int t = threadIdx.x;
    const int w = t >> 6, lane = t & 63, quad = lane >> 4, lr = lane & 15;
    const int wm = w >> 1, wn = w & 1;
    const u16* ag = a_t + blockIdx.x * (128 * 128);
    const u16* bg = b_t + blockIdx.y * (256 * 128);

    // ---- stage 2: direct-from-global fragments, no barriers ----
    f32x4 acc2[4][8] = {};
    for (int ks = 0; ks < 4; ks++) {
        const int k0 = ks * 32 + quad * 8;
        bf16x8 af[4], bfr[8];
        for (int tm = 0; tm < 4; tm++)
            af[tm] = *(const bf16x8*)(ag + (wm * 64 + tm * 16 + lr) * 128 + k0);
        for (int tn = 0; tn < 8; tn++)
            bfr[tn] = *(const bf16x8*)(bg + (wn * 128 + tn * 16 + lr) * 128 + k0);
        for (int tm = 0; tm < 4; tm++)
            for (int tn = 0; tn < 8; tn++)
                acc2[tm][tn] = __builtin_amdgcn_mfma_f32_16x16x32_bf16(
                    af[tm], bfr[tn], acc2[tm][tn], 0, 0, 0);
    }

    // ---- epilogue stage 2: conflict-free swizzled store to outer_s ----
    // value = outer[c][e], c = (tm&1)*16 + quad*4 + reg, e = (tn&1)*16 + lr
    for (int tm = 0; tm < 4; tm++)
        for (int tn = 0; tn < 8; tn++) {
            int p  = (wm * 2 + (tm >> 1)) * 8 + wn * 4 + (tn >> 1);
            int cI = (quad & 1) | ((lr >> 1) << 1) | ((quad >> 1) << 4)
                   | ((tn & 1) << 5) | ((tm & 1) << 6);
            int pi = cI ^ (p & 7);
            ushort4 o;
            o.x = f2bf(acc2[tm][tn][0]);
            o.y = f2bf(acc2[tm][tn][1]);
            o.z = f2bf(acc2[tm][tn][2]);
            o.w = f2bf(acc2[tm][tn][3]);
            *(ushort4*)(&outer_s[p * 1024 + pi * 8 + 4 * (lr & 1)]) = o;
        }
    __syncthreads();

    // ---- stage 3: [32 p][1024 k''] @ Wo_t -> [32 p][128 z] ----
    const int n0w = w * 32;
    const u16* wp0 = Wo_t + (n0w + lr) * 1024;
    const u16* wp1 = Wo_t + (n0w + 16 + lr) * 1024;
    f32x4 acc3[2][2] = {};
    bf16x8 b3c[2], b3n[2];
    {
        int k0 = quad * 8;
        b3c[0] = *(const bf16x8*)(wp0 + k0);
        b3c[1] = *(const bf16x8*)(wp1 + k0);
        b3n[0] = *(const bf16x8*)(wp0 + 32 + k0);
        b3n[1] = *(const bf16x8*)(wp1 + 32 + k0);
    }
    for (int ks = 0; ks < 32; ks++) {
        bf16x8 a3[2];
        for (int mt = 0; mt < 2; mt++) {
            int pi = ((ks * 4 + quad) ^ (lr & 7));
            a3[mt] = *(const bf16x8*)(&outer_s[(mt * 16 + lr) * 1024 + pi * 8]);
        }
        bf16x8 pf0, pf1;
        if (ks < 30) {
            int k2 = (ks + 2) * 32 + quad * 8;
            pf0 = *(const bf16x8*)(wp0 + k2);
            pf1 = *(const bf16x8*)(wp1 + k2);
        }
        for (int mt = 0; mt < 2; mt++) {
            acc3[mt][0] = __builtin_amdgcn_mfma_f32_16x16x32_bf16(a3[mt], b3c[0], acc3[mt][0], 0, 0, 0);
            acc3[mt][1] = __builtin_amdgcn_mfma_f32_16x16x32_bf16(a3[mt], b3c[1], acc3[mt][1], 0, 0, 0);
        }
        b3c[0] = b3n[0]; b3c[1] = b3n[1];
        b3n[0] = pf0;    b3n[1] = pf1;
    }

    // ---- epilogue: + bo, / norm, store ----
    const int i0 = blockIdx.x * 4, j0 = blockIdx.y * 8;
    for (int mt = 0; mt < 2; mt++)
        for (int reg = 0; reg < 4; reg++) {
            int p = mt * 16 + quad * 4 + reg;
            int ii = i0 + (p >> 3), jj = j0 + (p & 7);
            float nrm = norm_ws[ii * 256 + jj];
            for (int tt = 0; tt < 2; tt++) {
                int z = n0w + tt * 16 + lr;
                out[(ii * 256 + jj) * 128 + z] = (acc3[mt][tt][reg] + bo[z]) / nrm;
            }
        }
}

extern "C" void kernel_launch(void* const* d_in, const int* in_sizes, int n_in,
                              void* d_out, int out_size, void* d_ws, size_t ws_size,
                              hipStream_t stream)
{
    const float* m    = (const float*)d_in[0];
    const float* mask = (const float*)d_in[1];
    const float* ln_g = (const float*)d_in[2];
    const float* ln_b = (const float*)d_in[3];
    const float* Wa   = (const float*)d_in[4];
    const float* ba   = (const float*)d_in[5];
    const float* Wb   = (const float*)d_in[6];
    const float* bb   = (const float*)d_in[7];
    const float* Wo   = (const float*)d_in[8];
    const float* bo   = (const float*)d_in[9];
    float* out = (float*)d_out;

    char* ws = (char*)d_ws;
    u16*   a_t     = (u16*)ws;                        // 2 MB
    u16*   b_t     = (u16*)(ws + 0x200000);           // 2 MB
    u16*   Wo_t    = (u16*)(ws + 0x400000);           // 256 KB
    u16*   Wab_t   = (u16*)(ws + 0x440000);           // 32 KB
    float* norm_ws = (float*)(ws + 0x448000);         // 256 KB

    hipLaunchKernelGGL(kW, dim3(832), dim3(256), 0, stream,
                       Wo, Wa, Wb, mask, Wo_t, Wab_t, norm_ws);
    hipLaunchKernelGGL(kA, dim3(512), dim3(256), 0, stream,
                       m, mask, ln_g, ln_b, Wab_t, ba, bb, a_t, b_t);
    hipLaunchKernelGGL(kB, dim3(64, 32), dim3(256), 0, stream,
                       a_t, b_t, Wo_t, bo, norm_ws, out);
}

// Round 5
// 189.548 us; speedup vs baseline: 1.2233x; 1.2233x over previous
//
#include <hip/hip_runtime.h>

typedef unsigned short u16;
typedef short bf16x8 __attribute__((ext_vector_type(8)));
typedef float f32x4 __attribute__((ext_vector_type(4)));

#define CM 256

__device__ inline u16 f2bf(float f) {
    union { float f; unsigned u; } v; v.f = f;
    unsigned r = v.u + 0x7fffu + ((v.u >> 16) & 1u);
    return (u16)(r >> 16);
}

// ---------------------------------------------------------------------------
// k'' bit-interleave for the stage2->stage3 contraction index (c,e):
//   k''[0,1]=c[0,1]  k''[2]=e[0]  k''[3]=c[2]  k''[4:6]=e[1:3]
//   k''[7]=c[3]      k''[8]=e[4]  k''[9]=c[4]
// Valid because A and B just have to agree on k-order. Makes kB's epilogue
// stores 8B ushort4 (regs = 4 consecutive c) and, with pi = (k''>>3)^(p&7),
// spreads epilogue stores and a3 b128 reads over LDS banks (round-4 measured:
// conflicts 1.1e7 -> 3.1e6).
// ---------------------------------------------------------------------------

// kW: one-time prep (3 roles by blockIdx):
//  bid<512 : Wo[1024 ce][128 z] fp32 -> Wo_t[z][k''] bf16 (permuted)
//  bid<576 : Wa/Wb -> Wab_t[n][256 k] bf16 (n<32: Wa col, else Wb col)
//  else    : norm[i][j] = eps + sum_s mask[s,i]*mask[s,j]
__global__ void kW(const float* __restrict__ Wo, const float* __restrict__ Wa,
                   const float* __restrict__ Wb, const float* __restrict__ mask,
                   u16* __restrict__ Wo_t, u16* __restrict__ Wab_t,
                   float* __restrict__ norm_ws)
{
    int bid = blockIdx.x, t = threadIdx.x;
    if (bid < 512) {
        int idx = bid * 256 + t;            // idx = ce*128 + z (coalesced read)
        int ce = idx >> 7, z = idx & 127;
        int c = ce >> 5, e = ce & 31;
        int kpp = (c & 3) | ((e & 1) << 2) | (((c >> 2) & 1) << 3)
                | (((e >> 1) & 7) << 4) | (((c >> 3) & 1) << 7)
                | ((e >> 4) << 8) | ((c >> 4) << 9);
        Wo_t[z * 1024 + kpp] = f2bf(Wo[idx]);
    } else if (bid < 576) {
        int idx = (bid - 512) * 256 + t;    // idx = n*256 + k
        int n = idx >> 8, k = idx & 255;
        float v = (n < 32) ? Wa[k * 32 + n] : Wb[k * 32 + (n - 32)];
        Wab_t[idx] = f2bf(v);
    } else {
        int i = bid - 576, j = t;           // 256 blocks
        float acc = 1e-3f;
        for (int s = 0; s < 128; s++)
            acc += mask[s * 256 + i] * mask[s * 256 + j];
        norm_ws[i * 256 + j] = acc;
    }
}

// ---------------------------------------------------------------------------
// kA: LayerNorm + dual projection. Block = one i, 64 consecutive s (grid 512:
// blockIdx = i*2 + s_half). Per (i,c) output row this block writes 64
// CONTIGUOUS s as ushort4 -> full 64B sectors, no HBM read-modify-write
// (round-3/4 layout wrote single scattered u16 per 256B row -> partial-line
// writes). m reads stay 1 KB contiguous per row. LDS 33,792 B.
// ---------------------------------------------------------------------------
__global__ __launch_bounds__(256, 2) void kA(
    const float* __restrict__ m, const float* __restrict__ mask,
    const float* __restrict__ ln_g, const float* __restrict__ ln_b,
    const u16* __restrict__ Wab_t, const float* __restrict__ ba,
    const float* __restrict__ bb,
    u16* __restrict__ a_t, u16* __restrict__ b_t)
{
    __shared__ u16 mn_s[64 * 264];   // [local row r][k], stride 264 (pad 8)

    const int t = threadIdx.x;
    const int w = t >> 6, lane = t & 63, quad = lane >> 4, lr = lane & 15;
    const int i_idx = blockIdx.x >> 1;       // MSA column i
    const int sh = blockIdx.x & 1;           // s half: local r -> s = sh*64 + r

    bf16x8 wf[8];
    for (int ks = 0; ks < 8; ks++)
        wf[ks] = *(const bf16x8*)(Wab_t + (w * 16 + lr) * 256 + ks * 32 + quad * 8);

    const float4 g4  = ((const float4*)ln_g)[lane];
    const float4 be4 = ((const float4*)ln_b)[lane];

    for (int rr = 0; rr < 16; rr++) {
        int r = w * 16 + rr;
        int grow = (sh * 64 + r) * 256 + i_idx;      // flat (s,i) row index
        float4 x = ((const float4*)m)[grow * 64 + lane];
        float s1 = x.x + x.y + x.z + x.w;
        float s2 = x.x * x.x + x.y * x.y + x.z * x.z + x.w * x.w;
        for (int off = 32; off; off >>= 1) {
            s1 += __shfl_xor(s1, off);
            s2 += __shfl_xor(s2, off);
        }
        float mu = s1 * (1.f / CM);
        float rstd = rsqrtf(s2 * (1.f / CM) - mu * mu + 1e-5f);
        ushort4 o;
        o.x = f2bf((x.x - mu) * rstd * g4.x + be4.x);
        o.y = f2bf((x.y - mu) * rstd * g4.y + be4.y);
        o.z = f2bf((x.z - mu) * rstd * g4.z + be4.z);
        o.w = f2bf((x.w - mu) * rstd * g4.w + be4.w);
        *(ushort4*)(&mn_s[r * 264 + lane * 4]) = o;
    }
    __syncthreads();

    f32x4 acc[4] = {};
    for (int ks = 0; ks < 8; ks++)
        for (int mt = 0; mt < 4; mt++) {
            bf16x8 af = *(const bf16x8*)(&mn_s[(mt * 16 + lr) * 264 + ks * 32 + quad * 8]);
            acc[mt] = __builtin_amdgcn_mfma_f32_16x16x32_bf16(af, wf[ks], acc[mt], 0, 0, 0);
        }

    const int n = w * 16 + lr;          // C/D col
    const int cc = n & 31;
    const bool isB = n >= 32;
    const float bv = isB ? bb[cc] : ba[cc];
    u16* dst = isB ? b_t : a_t;
    for (int mt = 0; mt < 4; mt++) {
        int rbase = mt * 16 + quad * 4;          // C/D row base; reg contiguous
        int sbase = sh * 64 + rbase;
        ushort4 o;
        float v0 = (acc[mt][0] + bv) * mask[(sbase + 0) * 256 + i_idx];
        float v1 = (acc[mt][1] + bv) * mask[(sbase + 1) * 256 + i_idx];
        float v2 = (acc[mt][2] + bv) * mask[(sbase + 2) * 256 + i_idx];
        float v3 = (acc[mt][3] + bv) * mask[(sbase + 3) * 256 + i_idx];
        o.x = f2bf(v0); o.y = f2bf(v1); o.z = f2bf(v2); o.w = f2bf(v3);
        *(ushort4*)(dst + (i_idx * 32 + cc) * 128 + sbase) = o;
    }
}

// ---------------------------------------------------------------------------
// kB: fused outer-product + Wo projection. Tile 4i x 8j (32 pairs), grid
// (64,32), 256 thr. Stage 2: LDS-staged a/b tiles in two K=64 halves
// (round-3 structure — direct-global fragments spilled acc2 to scratch,
// +38 MB HBM writes, round-4 measured). Outer tile -> LDS bf16
// [32 p][1024 k''] with bit-interleave + XOR swizzle (round-4 measured
// -72% bank conflicts). Stage 3: M=32, K=1024, N=128, depth-2 Wo_t prefetch.
// LDS: 64 KB. ~128 arch VGPR + 128 acc -> 2 blocks/CU.
// ---------------------------------------------------------------------------
__global__ __launch_bounds__(256, 2) void kB(
    const u16* __restrict__ a_t, const u16* __restrict__ b_t,
    const u16* __restrict__ Wo_t, const float* __restrict__ bo,
    const float* __restrict__ norm_ws, float* __restrict__ out)
{
    __shared__ __align__(16) u16 smem[32768];     // 65,536 B
    u16* a_s = smem;                  // [128][72]
    u16* b_s = smem + 128 * 72;       // [256][72]
    u16* outer_s = smem;              // overlay after stage 2: [32][1024]

    const int t = threadIdx.x;
    const int w = t >> 6, lane = t & 63, quad = lane >> 4, lr = lane & 15;
    const int wm = w >> 1, wn = w & 1;
    const u16* ag = a_t + blockIdx.x * (128 * 128);
    const u16* bg = b_t + blockIdx.y * (256 * 128);

    // ---- stage 2: two K=64 halves through LDS ----
    f32x4 acc2[4][8] = {};
    for (int kh = 0; kh < 2; kh++) {
        for (int q = 0; q < 4; q++) {
            int flat = q * 2048 + t * 8;          // a: 128 rows x 64 k
            int mm = flat >> 6, kk = flat & 63;
            *(uint4*)(&a_s[mm * 72 + kk]) = *(const uint4*)(ag + mm * 128 + kh * 64 + kk);
        }
        for (int q = 0; q < 8; q++) {
            int flat = q * 2048 + t * 8;          // b: 256 rows x 64 k
            int mm = flat >> 6, kk = flat & 63;
            *(uint4*)(&b_s[mm * 72 + kk]) = *(const uint4*)(bg + mm * 128 + kh * 64 + kk);
        }
        __syncthreads();
        for (int ks = 0; ks < 2; ks++) {
            int k0 = ks * 32 + quad * 8;
            bf16x8 af[4], bfr[8];
            for (int tm = 0; tm < 4; tm++)
                af[tm] = *(const bf16x8*)(&a_s[(wm * 64 + tm * 16 + lr) * 72 + k0]);
            for (int tn = 0; tn < 8; tn++)
                bfr[tn] = *(const bf16x8*)(&b_s[(wn * 128 + tn * 16 + lr) * 72 + k0]);
            for (int tm = 0; tm < 4; tm++)
                for (int tn = 0; tn < 8; tn++)
                    acc2[tm][tn] = __builtin_amdgcn_mfma_f32_16x16x32_bf16(
                        af[tm], bfr[tn], acc2[tm][tn], 0, 0, 0);
        }
        __syncthreads();
    }

    // ---- epilogue stage 2: swizzled packed store to outer_s ----
    // value = outer[c][e]; c = (tm&1)*16 + quad*4 + reg, e = (tn&1)*16 + lr
    // p = i_l*8 + j_l, i_l = wm*2 + (tm>>1), j_l = wn*4 + (tn>>1)
    for (int tm = 0; tm < 4; tm++)
        for (int tn = 0; tn < 8; tn++) {
            int p  = (wm * 2 + (tm >> 1)) * 8 + wn * 4 + (tn >> 1);
            int cI = (quad & 1) | ((lr >> 1) << 1) | ((quad >> 1) << 4)
                   | ((tn & 1) << 5) | ((tm & 1) << 6);
            int pi = cI ^ (p & 7);
            ushort4 o;
            o.x = f2bf(acc2[tm][tn][0]);
            o.y = f2bf(acc2[tm][tn][1]);
            o.z = f2bf(acc2[tm][tn][2]);
            o.w = f2bf(acc2[tm][tn][3]);
            *(ushort4*)(&outer_s[p * 1024 + pi * 8 + 4 * (lr & 1)]) = o;
        }
    __syncthreads();

    // ---- stage 3: [32 p][1024 k''] @ Wo_t -> [32 p][128 z] ----
    const int n0w = w * 32;
    const u16* wp0 = Wo_t + (n0w + lr) * 1024;
    const u16* wp1 = Wo_t + (n0w + 16 + lr) * 1024;
    f32x4 acc3[2][2] = {};
    bf16x8 b3c[2], b3n[2];
    {
        int k0 = quad * 8;
        b3c[0] = *(const bf16x8*)(wp0 + k0);
        b3c[1] = *(const bf16x8*)(wp1 + k0);
        b3n[0] = *(const bf16x8*)(wp0 + 32 + k0);
        b3n[1] = *(const bf16x8*)(wp1 + 32 + k0);
    }
    for (int ks = 0; ks < 32; ks++) {
        bf16x8 a3[2];
        for (int mt = 0; mt < 2; mt++) {
            int pi = ((ks * 4 + quad) ^ (lr & 7));
            a3[mt] = *(const bf16x8*)(&outer_s[(mt * 16 + lr) * 1024 + pi * 8]);
        }
        bf16x8 pf0, pf1;
        if (ks < 30) {
            int k2 = (ks + 2) * 32 + quad * 8;
            pf0 = *(const bf16x8*)(wp0 + k2);
            pf1 = *(const bf16x8*)(wp1 + k2);
        }
        for (int mt = 0; mt < 2; mt++) {
            acc3[mt][0] = __builtin_amdgcn_mfma_f32_16x16x32_bf16(a3[mt], b3c[0], acc3[mt][0], 0, 0, 0);
            acc3[mt][1] = __builtin_amdgcn_mfma_f32_16x16x32_bf16(a3[mt], b3c[1], acc3[mt][1], 0, 0, 0);
        }
        b3c[0] = b3n[0]; b3c[1] = b3n[1];
        b3n[0] = pf0;    b3n[1] = pf1;
    }

    // ---- epilogue: + bo, / norm, store ----
    const int i0 = blockIdx.x * 4, j0 = blockIdx.y * 8;
    for (int mt = 0; mt < 2; mt++)
        for (int reg = 0; reg < 4; reg++) {
            int p = mt * 16 + quad * 4 + reg;
            int ii = i0 + (p >> 3), jj = j0 + (p & 7);
            float nrm = norm_ws[ii * 256 + jj];
            for (int tt = 0; tt < 2; tt++) {
                int z = n0w + tt * 16 + lr;
                out[(ii * 256 + jj) * 128 + z] = (acc3[mt][tt][reg] + bo[z]) / nrm;
            }
        }
}

extern "C" void kernel_launch(void* const* d_in, const int* in_sizes, int n_in,
                              void* d_out, int out_size, void* d_ws, size_t ws_size,
                              hipStream_t stream)
{
    const float* m    = (const float*)d_in[0];
    const float* mask = (const float*)d_in[1];
    const float* ln_g = (const float*)d_in[2];
    const float* ln_b = (const float*)d_in[3];
    const float* Wa   = (const float*)d_in[4];
    const float* ba   = (const float*)d_in[5];
    const float* Wb   = (const float*)d_in[6];
    const float* bb   = (const float*)d_in[7];
    const float* Wo   = (const float*)d_in[8];
    const float* bo   = (const float*)d_in[9];
    float* out = (float*)d_out;

    char* ws = (char*)d_ws;
    u16*   a_t     = (u16*)ws;                        // 2 MB
    u16*   b_t     = (u16*)(ws + 0x200000);           // 2 MB
    u16*   Wo_t    = (u16*)(ws + 0x400000);           // 256 KB
    u16*   Wab_t   = (u16*)(ws + 0x440000);           // 32 KB
    float* norm_ws = (float*)(ws + 0x448000);         // 256 KB

    hipLaunchKernelGGL(kW, dim3(832), dim3(256), 0, stream,
                       Wo, Wa, Wb, mask, Wo_t, Wab_t, norm_ws);
    hipLaunchKernelGGL(kA, dim3(512), dim3(256), 0, stream,
                       m, mask, ln_g, ln_b, Wab_t, ba, bb, a_t, b_t);
    hipLaunchKernelGGL(kB, dim3(64, 32), dim3(256), 0, stream,
                       a_t, b_t, Wo_t, bo, norm_ws, out);
}